// Round 12
// baseline (84.083 us; speedup 1.0000x reference)
//
#include <hip/hip_runtime.h>
#include <math.h>

#define EPS 1e-4f
#define N_   32
#define CIN  128
#define L_   512
#define CP   64
#define P_   2000
#define NCLS 200

typedef __attribute__((ext_vector_type(8))) short bf16x8;
typedef __attribute__((ext_vector_type(4))) float f32x4;

__device__ inline unsigned short f2bf_rne(float f) {
    unsigned int u = __float_as_uint(f);
    unsigned int r = u + 0x7FFFu + ((u >> 16) & 1u);
    return (unsigned short)(r >> 16);
}
__device__ inline float bf2f(unsigned short h) {
    return __uint_as_float(((unsigned int)h) << 16);
}

__device__ inline void gl_lds16(const void* g, void* l) {
    __builtin_amdgcn_global_load_lds(
        (const __attribute__((address_space(1))) unsigned int*)g,
        (__attribute__((address_space(3))) unsigned int*)l, 16, 0, 0);
}

// ---------------- Kernel 0: proto f32 -> split bf16 (hi/lo) + p2 ----------------
__global__ __launch_bounds__(256) void k0_proto(const float* __restrict__ proto,
    unsigned short* __restrict__ ph, unsigned short* __restrict__ pl,
    float* __restrict__ p2)
{
    const int tid = threadIdx.x;
    const int p   = blockIdx.x*4 + (tid >> 6);
    const int k   = tid & 63;
    float v = proto[(size_t)p*64 + k];
    unsigned short hb = f2bf_rne(v);
    unsigned short lb = f2bf_rne(v - bf2f(hb));
    ph[(size_t)p*64 + k] = hb;
    pl[(size_t)p*64 + k] = lb;
    float s = v*v;
    #pragma unroll
    for (int off = 32; off > 0; off >>= 1) s += __shfl_xor(s, off);
    if (k == 0) p2[p] = s;
}

// ---------------- Kernel 1: conv1x1 -> relu -> conv1x1 -> sigmoid ----------------
__global__ __launch_bounds__(256) void k1_conv(const float* __restrict__ x,
    const float* __restrict__ W1, const float* __restrict__ b1,
    const float* __restrict__ W2, const float* __restrict__ b2,
    unsigned short* __restrict__ fTh, unsigned short* __restrict__ fTl,
    float* __restrict__ x2buf)
{
    __shared__ float  xS[128*32];              // 16KB [c][l]
    __shared__ float4 W1s[64][32];             // 32KB [o][c4]
    __shared__ float4 W2s[64][16];             // 16KB [o][c4]
    __shared__ __align__(16) char scratch[8448];  // hS [64][33] f32  OR  fP [2][32][8] uint4
    __shared__ float  x2p[8][32];
    __shared__ float  b1s[64], b2s[64];

    float (*hS)[33]    = (float (*)[33])scratch;
    uint4 (*fP)[32][8] = (uint4 (*)[32][8])scratch;

    const int tid = threadIdx.x;
    const int wv  = tid >> 6;
    const int n   = blockIdx.y;
    const int lg  = blockIdx.x;

    {
        const float* xbase = x + (size_t)n*CIN*L_ + lg*32;
        const int lane = tid & 63;
        #pragma unroll
        for (int i = 0; i < 4; ++i) {
            int blk = wv*4 + i;
            const float* src = xbase + (size_t)(blk*8 + (lane >> 3))*L_ + (lane & 7)*4;
            gl_lds16(src, &xS[blk*256]);
        }
    }

    const float4* W1g = (const float4*)W1;
    #pragma unroll
    for (int i = 0; i < 8; ++i) {
        int idx = tid + i*256;
        W1s[idx >> 5][idx & 31] = W1g[idx];
    }
    const float4* W2g = (const float4*)W2;
    #pragma unroll
    for (int i = 0; i < 4; ++i) {
        int idx = tid + i*256;
        W2s[idx >> 4][idx & 15] = W2g[idx];
    }
    if (tid < 64) { b1s[tid] = b1[tid]; b2s[tid] = b2[tid]; }
    __syncthreads();

    const int l  = tid & 31;
    const int og = tid >> 5;

    float h[8];
    #pragma unroll
    for (int o = 0; o < 8; ++o) h[o] = b1s[og*8 + o];

    #pragma unroll 8
    for (int c4 = 0; c4 < 32; ++c4) {
        float xv0 = xS[(c4*4+0)*32 + l];
        float xv1 = xS[(c4*4+1)*32 + l];
        float xv2 = xS[(c4*4+2)*32 + l];
        float xv3 = xS[(c4*4+3)*32 + l];
        #pragma unroll
        for (int o = 0; o < 8; ++o) {
            float4 w = W1s[og*8+o][c4];
            h[o] = fmaf(w.x, xv0, fmaf(w.y, xv1, fmaf(w.z, xv2, fmaf(w.w, xv3, h[o]))));
        }
    }
    __syncthreads();
    #pragma unroll
    for (int o = 0; o < 8; ++o)
        hS[og*8+o][l] = fmaxf(h[o], 0.0f);
    __syncthreads();

    float f[8];
    #pragma unroll
    for (int o = 0; o < 8; ++o) f[o] = b2s[og*8 + o];
    #pragma unroll 4
    for (int c4 = 0; c4 < 16; ++c4) {
        float h0 = hS[c4*4+0][l];
        float h1 = hS[c4*4+1][l];
        float h2 = hS[c4*4+2][l];
        float h3 = hS[c4*4+3][l];
        #pragma unroll
        for (int o = 0; o < 8; ++o) {
            float4 w = W2s[og*8+o][c4];
            f[o] = fmaf(w.x, h0, fmaf(w.y, h1, fmaf(w.z, h2, fmaf(w.w, h3, f[o]))));
        }
    }

    unsigned int packH[4], packL[4];
    float s = 0.0f;
    #pragma unroll
    for (int o = 0; o < 8; ++o) {
        float v = 1.0f / (1.0f + expf(-f[o]));
        unsigned short hb = f2bf_rne(v);
        unsigned short lb = f2bf_rne(v - bf2f(hb));
        if (o & 1) { packH[o>>1] |= ((unsigned)hb) << 16; packL[o>>1] |= ((unsigned)lb) << 16; }
        else       { packH[o>>1] = hb;                     packL[o>>1] = lb; }
        s = fmaf(v, v, s);
    }
    x2p[og][l] = s;
    __syncthreads();

    fP[0][l][og ^ (l & 7)] = make_uint4(packH[0],packH[1],packH[2],packH[3]);
    fP[1][l][og ^ (l & 7)] = make_uint4(packL[0],packL[1],packL[2],packL[3]);
    __syncthreads();

    uint4* gH4 = (uint4*)fTh + ((size_t)(n*L_ + lg*32))*8;
    uint4* gL4 = (uint4*)fTl + ((size_t)(n*L_ + lg*32))*8;
    {
        int ll = tid >> 3, u = tid & 7;
        gH4[tid] = fP[0][ll][u ^ (ll & 7)];
        gL4[tid] = fP[1][ll][u ^ (ll & 7)];
    }
    if (tid < 32) {
        float v = 0.f;
        #pragma unroll
        for (int g = 0; g < 8; ++g) v += x2p[g][tid];
        x2buf[n*L_ + lg*32 + tid] = v;
    }
}

// ---------------- Kernel 2: SWAPPED-OPERAND distance scan (R11 version, unchanged) --------
__global__ __launch_bounds__(512) void k2_dist(
    const unsigned short* __restrict__ fTh, const unsigned short* __restrict__ fTl,
    const unsigned short* __restrict__ ph, const unsigned short* __restrict__ pl,
    const float* __restrict__ x2buf, float* __restrict__ md_part)
{
    __shared__ unsigned short fBh[4096];  // [64 l][64 k] bf16, XOR-swizzled rows (8KB)
    __shared__ unsigned short fBl[4096];
    __shared__ float x2S[64];

    const int tid  = threadIdx.x;
    const int lane = tid & 63;
    const int wv   = tid >> 6;          // 0..7
    const int n    = blockIdx.y;
    const int lg   = blockIdx.x;        // 0..7, 64 l each

    {
        const char* gH = (const char*)(fTh + ((size_t)n*L_ + lg*64)*CP);
        const char* gL = (const char*)(fTl + ((size_t)n*L_ + lg*64)*CP);
        int d  = tid * 16;
        int lr = d >> 7;
        int bo = d & 127;
        int pb = (lr << 7) + (bo ^ ((lr & 7) << 4));
        *(uint4*)((char*)fBh + pb) = *(const uint4*)(gH + d);
        *(uint4*)((char*)fBl + pb) = *(const uint4*)(gL + d);
    }
    if (tid < 64) x2S[tid] = x2buf[n*L_ + lg*64 + tid];
    __syncthreads();

    const int g  = lane >> 4;           // 0..3
    const int pr = lane & 15;

    bf16x8 ah[4][2], alo[4][2];
    #pragma unroll
    for (int lt = 0; lt < 4; ++lt) {
        int lrow = lt*16 + pr;
        #pragma unroll
        for (int ks = 0; ks < 2; ++ks) {
            int bo = (ks*64 + g*16) ^ ((lrow & 7) << 4);
            ah[lt][ks]  = *(const bf16x8*)((const char*)fBh + lrow*128 + bo);
            alo[lt][ks] = *(const bf16x8*)((const char*)fBl + lrow*128 + bo);
        }
    }
    float4 xv[4];
    #pragma unroll
    for (int lt = 0; lt < 4; ++lt)
        xv[lt] = *(const float4*)&x2S[lt*16 + g*4];

    float* mp = md_part + ((size_t)lg*N_ + n)*P_;

    bf16x8 b_h[2], b_l[2], nb_h[2], nb_l[2];
    {
        const int p = wv*16 + pr;
        #pragma unroll
        for (int ks = 0; ks < 2; ++ks) {
            b_h[ks] = *(const bf16x8*)(ph + (size_t)p*64 + ks*32 + g*8);
            b_l[ks] = *(const bf16x8*)(pl + (size_t)p*64 + ks*32 + g*8);
        }
    }
    for (int pt = wv; pt < P_/16; pt += 8) {
        const int ptn = pt + 8;
        if (ptn < P_/16) {
            const int p = ptn*16 + pr;
            #pragma unroll
            for (int ks = 0; ks < 2; ++ks) {
                nb_h[ks] = *(const bf16x8*)(ph + (size_t)p*64 + ks*32 + g*8);
                nb_l[ks] = *(const bf16x8*)(pl + (size_t)p*64 + ks*32 + g*8);
            }
        }

        float cm0 = 3.0e38f, cm1 = 3.0e38f, cm2 = 3.0e38f, cm3 = 3.0e38f;
        #pragma unroll
        for (int lt = 0; lt < 4; ++lt) {
            f32x4 c = {0.f, 0.f, 0.f, 0.f};
            c = __builtin_amdgcn_mfma_f32_16x16x32_bf16(ah[lt][0],  b_h[0], c, 0, 0, 0);
            c = __builtin_amdgcn_mfma_f32_16x16x32_bf16(ah[lt][1],  b_h[1], c, 0, 0, 0);
            c = __builtin_amdgcn_mfma_f32_16x16x32_bf16(alo[lt][0], b_h[0], c, 0, 0, 0);
            c = __builtin_amdgcn_mfma_f32_16x16x32_bf16(alo[lt][1], b_h[1], c, 0, 0, 0);
            c = __builtin_amdgcn_mfma_f32_16x16x32_bf16(ah[lt][0],  b_l[0], c, 0, 0, 0);
            c = __builtin_amdgcn_mfma_f32_16x16x32_bf16(ah[lt][1],  b_l[1], c, 0, 0, 0);
            cm0 = fminf(cm0, fmaf(-2.f, c[0], xv[lt].x));
            cm1 = fminf(cm1, fmaf(-2.f, c[1], xv[lt].y));
            cm2 = fminf(cm2, fmaf(-2.f, c[2], xv[lt].z));
            cm3 = fminf(cm3, fmaf(-2.f, c[3], xv[lt].w));
        }
        float v = fminf(fminf(cm0, cm1), fminf(cm2, cm3));
        v = fminf(v, __shfl_xor(v, 16));
        v = fminf(v, __shfl_xor(v, 32));
        if (lane < 16) mp[pt*16 + lane] = v;

        #pragma unroll
        for (int ks = 0; ks < 2; ++ks) {
            b_h[ks] = nb_h[ks]; b_l[ks] = nb_l[ks];
        }
    }
}

// ---------------- Kernel 2b: min over 8 l-chunks + p2 + relu + log ----------------
__global__ __launch_bounds__(256) void k2b_reduce(const float* __restrict__ md_part,
    const float* __restrict__ p2, float* __restrict__ md_out, float* __restrict__ acts)
{
    const int p = blockIdx.x*256 + threadIdx.x;
    const int n = blockIdx.y;
    if (p < P_) {
        float mv = 3.0e38f;
        #pragma unroll
        for (int lg = 0; lg < 8; ++lg)
            mv = fminf(mv, md_part[((size_t)lg*N_ + n)*P_ + p]);
        float m = fmaxf(mv + p2[p], 0.0f);
        md_out[n*P_ + p] = m;
        acts[n*P_ + p]   = logf((m + 1.0f) / (m + EPS));
    }
}

// ---------------- Kernel 3: logits = acts @ last_w^T, one wave per output ----------------
__global__ __launch_bounds__(256) void k3_logits(const float* __restrict__ acts,
    const float* __restrict__ last_w, float* __restrict__ out)
{
    const int wid  = (blockIdx.x * 256 + threadIdx.x) >> 6;  // 0..6399
    const int lane = threadIdx.x & 63;
    const int n    = wid / NCLS;
    const int cls  = wid - n * NCLS;

    const float4* a = (const float4*)(acts + (size_t)n*P_);
    const float4* w = (const float4*)(last_w + (size_t)cls*P_);

    float acc = 0.f;
    #pragma unroll
    for (int it = 0; it < 8; ++it) {
        int idx = it*64 + lane;
        if (idx < P_/4) {
            float4 av = a[idx]; float4 wv = w[idx];
            acc += av.x*wv.x + av.y*wv.y + av.z*wv.z + av.w*wv.w;
        }
    }
    #pragma unroll
    for (int off = 32; off > 0; off >>= 1)
        acc += __shfl_down(acc, off);
    if (lane == 0)
        out[n*NCLS + cls] = acc;
}

extern "C" void kernel_launch(void* const* d_in, const int* in_sizes, int n_in,
                              void* d_out, int out_size, void* d_ws, size_t ws_size,
                              hipStream_t stream)
{
    const float* x      = (const float*)d_in[0];
    const float* W1     = (const float*)d_in[1];
    const float* b1     = (const float*)d_in[2];
    const float* W2     = (const float*)d_in[3];
    const float* b2     = (const float*)d_in[4];
    const float* proto  = (const float*)d_in[5];
    const float* last_w = (const float*)d_in[6];

    float* out = (float*)d_out;   // [32*200] logits, then [32*2000] min_dist

    // ws layout (≈6.9MB):
    // fTh 2MB | fTl 2MB | x2buf 64KB | acts 256KB | ph 256KB | pl 256KB | p2 8KB | md_part 2MB
    unsigned short* fTh = (unsigned short*)d_ws;
    unsigned short* fTl = fTh + (size_t)N_*L_*CP;
    float* x2buf = (float*)(fTl + (size_t)N_*L_*CP);
    float* acts  = x2buf + (size_t)N_*L_;
    unsigned short* ph = (unsigned short*)(acts + (size_t)N_*P_);
    unsigned short* pl = ph + (size_t)P_*CP;
    float* p2      = (float*)(pl + (size_t)P_*CP);
    float* md_part = p2 + P_;

    k0_proto  <<<500,          256, 0, stream>>>(proto, ph, pl, p2);
    k1_conv   <<<dim3(16, 32), 256, 0, stream>>>(x, W1, b1, W2, b2, fTh, fTl, x2buf);
    // --- MEASUREMENT: k2 launched 3x (idempotent). dur_us delta vs R11 = 2x k2 cost. ---
    k2_dist   <<<dim3(8, 32),  512, 0, stream>>>(fTh, fTl, ph, pl, x2buf, md_part);
    k2_dist   <<<dim3(8, 32),  512, 0, stream>>>(fTh, fTl, ph, pl, x2buf, md_part);
    k2_dist   <<<dim3(8, 32),  512, 0, stream>>>(fTh, fTl, ph, pl, x2buf, md_part);
    k2b_reduce<<<dim3(8, 32),  256, 0, stream>>>(md_part, p2, out + N_*NCLS, acts);
    k3_logits <<<1600,         256, 0, stream>>>(acts, last_w, out);
}

// Round 13
// 46.615 us; speedup vs baseline: 1.8038x; 1.8038x over previous
//
#include <hip/hip_runtime.h>
#include <hip/hip_fp16.h>
#include <math.h>

#define EPS 1e-4f
#define N_   32
#define CIN  128
#define L_   512
#define CP   64
#define P_   2000
#define NCLS 200

typedef __attribute__((ext_vector_type(8))) _Float16 f16x8;
typedef __attribute__((ext_vector_type(4))) float f32x4;

__device__ inline void gl_lds16(const void* g, void* l) {
    __builtin_amdgcn_global_load_lds(
        (const __attribute__((address_space(1))) unsigned int*)g,
        (__attribute__((address_space(3))) unsigned int*)l, 16, 0, 0);
}

// ---------------- Kernel 0: proto f32 -> f16 + p2 ----------------
__global__ __launch_bounds__(256) void k0_proto(const float* __restrict__ proto,
    unsigned short* __restrict__ ph, float* __restrict__ p2)
{
    const int tid = threadIdx.x;
    const int p   = blockIdx.x*4 + (tid >> 6);
    const int k   = tid & 63;
    float v = proto[(size_t)p*64 + k];
    ph[(size_t)p*64 + k] = __half_as_ushort(__float2half(v));
    float s = v*v;
    #pragma unroll
    for (int off = 32; off > 0; off >>= 1) s += __shfl_xor(s, off);
    if (k == 0) p2[p] = s;
}

// ---------------- Kernel 1: conv1x1 -> relu -> conv1x1 -> sigmoid -> f16 ----------------
// 512 blocks (2/CU): block = (n, 32 l). thread = (og: 8-ch group, l).
__global__ __launch_bounds__(256) void k1_conv(const float* __restrict__ x,
    const float* __restrict__ W1, const float* __restrict__ b1,
    const float* __restrict__ W2, const float* __restrict__ b2,
    unsigned short* __restrict__ fT, float* __restrict__ x2buf)
{
    __shared__ float  xS[128*32];              // 16KB [c][l]
    __shared__ float4 W1s[64][32];             // 32KB [o][c4]
    __shared__ float4 W2s[64][16];             // 16KB [o][c4]
    __shared__ __align__(16) char scratch[8448];  // hS [64][33] f32  OR  fP [32][8] uint4
    __shared__ float  x2p[8][32];
    __shared__ float  b1s[64], b2s[64];

    float (*hS)[33]    = (float (*)[33])scratch;
    uint4 (*fP)[8]     = (uint4 (*)[8])scratch;

    const int tid = threadIdx.x;
    const int wv  = tid >> 6;
    const int n   = blockIdx.y;
    const int lg  = blockIdx.x;

    {
        const float* xbase = x + (size_t)n*CIN*L_ + lg*32;
        const int lane = tid & 63;
        #pragma unroll
        for (int i = 0; i < 4; ++i) {
            int blk = wv*4 + i;
            const float* src = xbase + (size_t)(blk*8 + (lane >> 3))*L_ + (lane & 7)*4;
            gl_lds16(src, &xS[blk*256]);
        }
    }

    const float4* W1g = (const float4*)W1;
    #pragma unroll
    for (int i = 0; i < 8; ++i) {
        int idx = tid + i*256;
        W1s[idx >> 5][idx & 31] = W1g[idx];
    }
    const float4* W2g = (const float4*)W2;
    #pragma unroll
    for (int i = 0; i < 4; ++i) {
        int idx = tid + i*256;
        W2s[idx >> 4][idx & 15] = W2g[idx];
    }
    if (tid < 64) { b1s[tid] = b1[tid]; b2s[tid] = b2[tid]; }
    __syncthreads();

    const int l  = tid & 31;
    const int og = tid >> 5;

    float h[8];
    #pragma unroll
    for (int o = 0; o < 8; ++o) h[o] = b1s[og*8 + o];

    #pragma unroll 8
    for (int c4 = 0; c4 < 32; ++c4) {
        float xv0 = xS[(c4*4+0)*32 + l];
        float xv1 = xS[(c4*4+1)*32 + l];
        float xv2 = xS[(c4*4+2)*32 + l];
        float xv3 = xS[(c4*4+3)*32 + l];
        #pragma unroll
        for (int o = 0; o < 8; ++o) {
            float4 w = W1s[og*8+o][c4];
            h[o] = fmaf(w.x, xv0, fmaf(w.y, xv1, fmaf(w.z, xv2, fmaf(w.w, xv3, h[o]))));
        }
    }
    __syncthreads();   // xS done; scratch -> hS
    #pragma unroll
    for (int o = 0; o < 8; ++o)
        hS[og*8+o][l] = fmaxf(h[o], 0.0f);
    __syncthreads();

    float f[8];
    #pragma unroll
    for (int o = 0; o < 8; ++o) f[o] = b2s[og*8 + o];
    #pragma unroll 4
    for (int c4 = 0; c4 < 16; ++c4) {
        float h0 = hS[c4*4+0][l];
        float h1 = hS[c4*4+1][l];
        float h2 = hS[c4*4+2][l];
        float h3 = hS[c4*4+3][l];
        #pragma unroll
        for (int o = 0; o < 8; ++o) {
            float4 w = W2s[og*8+o][c4];
            f[o] = fmaf(w.x, h0, fmaf(w.y, h1, fmaf(w.z, h2, fmaf(w.w, h3, f[o]))));
        }
    }

    unsigned int pack[4];
    float s = 0.0f;
    #pragma unroll
    for (int o = 0; o < 8; ++o) {
        float v = 1.0f / (1.0f + expf(-f[o]));
        unsigned short hb = __half_as_ushort(__float2half(v));
        if (o & 1) pack[o>>1] |= ((unsigned)hb) << 16;
        else       pack[o>>1]  = hb;
        s = fmaf(v, v, s);
    }
    x2p[og][l] = s;
    __syncthreads();   // hS done; scratch -> fP bounce

    fP[l][og ^ (l & 7)] = make_uint4(pack[0],pack[1],pack[2],pack[3]);
    __syncthreads();

    // coalesced stores: [n][l][c] f16, 64 c per l = 8 uint4
    uint4* g4 = (uint4*)fT + ((size_t)(n*L_ + lg*32))*8;
    {
        int ll = tid >> 3, u = tid & 7;
        g4[tid] = fP[ll][u ^ (ll & 7)];
    }
    if (tid < 32) {
        float v = 0.f;
        #pragma unroll
        for (int g = 0; g < 8; ++g) v += x2p[g][tid];
        x2buf[n*L_ + lg*32 + tid] = v;
    }
}

// ---------------- Kernel 2: single-pass f16 MFMA distance scan ----------------
// A = f (rows = l), B = proto (cols = p) => D[l][p]; l-min = reg fold + 2 shfl.
// grid (8 lg x 4 pg, 32 n) x 256 thr (4 waves) = 1024 blocks -> 4 blocks/CU.
// wave wv of block pg handles tiles t = pg + 4*wv + 16*k (125 tiles total).
__global__ __launch_bounds__(256) void k2_dist(
    const unsigned short* __restrict__ fT, const unsigned short* __restrict__ ph,
    const float* __restrict__ x2buf, float* __restrict__ md_part)
{
    __shared__ unsigned short fB[4096];  // [64 l][64 k] f16, XOR-swizzled rows (8KB)
    __shared__ float x2S[64];

    const int tid  = threadIdx.x;
    const int lane = tid & 63;
    const int wv   = tid >> 6;          // 0..3
    const int n    = blockIdx.y;
    const int lg   = blockIdx.x >> 2;   // 0..7, 64 l each
    const int pg   = blockIdx.x & 3;    // 0..3 proto-tile phase

    {
        const char* gH = (const char*)(fT + ((size_t)n*L_ + lg*64)*CP);
        #pragma unroll
        for (int j = 0; j < 2; ++j) {
            int d  = tid*32 + j*16;
            int lr = d >> 7;
            int bo = d & 127;
            int pb = (lr << 7) + (bo ^ ((lr & 7) << 4));
            *(uint4*)((char*)fB + pb) = *(const uint4*)(gH + d);
        }
    }
    if (tid < 64) x2S[tid] = x2buf[n*L_ + lg*64 + tid];
    __syncthreads();

    const int g  = lane >> 4;           // 0..3
    const int pr = lane & 15;

    // ---- A fragments: f rows (l = lt*16 + pr) ----
    f16x8 af[4][2];
    #pragma unroll
    for (int lt = 0; lt < 4; ++lt) {
        int lrow = lt*16 + pr;
        #pragma unroll
        for (int ks = 0; ks < 2; ++ks) {
            int bo = (ks*64 + g*16) ^ ((lrow & 7) << 4);
            af[lt][ks] = *(const f16x8*)((const char*)fB + lrow*128 + bo);
        }
    }
    float4 xv[4];
    #pragma unroll
    for (int lt = 0; lt < 4; ++lt)
        xv[lt] = *(const float4*)&x2S[lt*16 + g*4];

    float* mp = md_part + ((size_t)lg*N_ + n)*P_;

    // ---- stream proto tiles with 1-deep prefetch ----
    const int t0 = pg + 4*wv;           // 0..15
    f16x8 b[2], nb[2];
    {
        const int p = t0*16 + pr;
        #pragma unroll
        for (int ks = 0; ks < 2; ++ks)
            b[ks] = *(const f16x8*)(ph + (size_t)p*64 + ks*32 + g*8);
    }
    for (int t = t0; t < P_/16; t += 16) {
        const int tn = t + 16;
        if (tn < P_/16) {
            const int p = tn*16 + pr;
            #pragma unroll
            for (int ks = 0; ks < 2; ++ks)
                nb[ks] = *(const f16x8*)(ph + (size_t)p*64 + ks*32 + g*8);
        }

        float cm0 = 3.0e38f, cm1 = 3.0e38f, cm2 = 3.0e38f, cm3 = 3.0e38f;
        #pragma unroll
        for (int lt = 0; lt < 4; ++lt) {
            f32x4 c = {0.f, 0.f, 0.f, 0.f};
            c = __builtin_amdgcn_mfma_f32_16x16x32_f16(af[lt][0], b[0], c, 0, 0, 0);
            c = __builtin_amdgcn_mfma_f32_16x16x32_f16(af[lt][1], b[1], c, 0, 0, 0);
            cm0 = fminf(cm0, fmaf(-2.f, c[0], xv[lt].x));
            cm1 = fminf(cm1, fmaf(-2.f, c[1], xv[lt].y));
            cm2 = fminf(cm2, fmaf(-2.f, c[2], xv[lt].z));
            cm3 = fminf(cm3, fmaf(-2.f, c[3], xv[lt].w));
        }
        float v = fminf(fminf(cm0, cm1), fminf(cm2, cm3));
        v = fminf(v, __shfl_xor(v, 16));
        v = fminf(v, __shfl_xor(v, 32));
        if (lane < 16) mp[t*16 + lane] = v;

        b[0] = nb[0]; b[1] = nb[1];
    }
}

// ---------------- Kernel 2b: min over 8 l-chunks + p2 + relu + log ----------------
__global__ __launch_bounds__(256) void k2b_reduce(const float* __restrict__ md_part,
    const float* __restrict__ p2, float* __restrict__ md_out, float* __restrict__ acts)
{
    const int p = blockIdx.x*256 + threadIdx.x;
    const int n = blockIdx.y;
    if (p < P_) {
        float mv = 3.0e38f;
        #pragma unroll
        for (int lg = 0; lg < 8; ++lg)
            mv = fminf(mv, md_part[((size_t)lg*N_ + n)*P_ + p]);
        float m = fmaxf(mv + p2[p], 0.0f);
        md_out[n*P_ + p] = m;
        acts[n*P_ + p]   = logf((m + 1.0f) / (m + EPS));
    }
}

// ---------------- Kernel 3: logits = acts @ last_w^T, one wave per output ----------------
__global__ __launch_bounds__(256) void k3_logits(const float* __restrict__ acts,
    const float* __restrict__ last_w, float* __restrict__ out)
{
    const int wid  = (blockIdx.x * 256 + threadIdx.x) >> 6;  // 0..6399
    const int lane = threadIdx.x & 63;
    const int n    = wid / NCLS;
    const int cls  = wid - n * NCLS;

    const float4* a = (const float4*)(acts + (size_t)n*P_);
    const float4* w = (const float4*)(last_w + (size_t)cls*P_);

    float acc = 0.f;
    #pragma unroll
    for (int it = 0; it < 8; ++it) {
        int idx = it*64 + lane;
        if (idx < P_/4) {
            float4 av = a[idx]; float4 wv = w[idx];
            acc += av.x*wv.x + av.y*wv.y + av.z*wv.z + av.w*wv.w;
        }
    }
    #pragma unroll
    for (int off = 32; off > 0; off >>= 1)
        acc += __shfl_down(acc, off);
    if (lane == 0)
        out[n*NCLS + cls] = acc;
}

extern "C" void kernel_launch(void* const* d_in, const int* in_sizes, int n_in,
                              void* d_out, int out_size, void* d_ws, size_t ws_size,
                              hipStream_t stream)
{
    const float* x      = (const float*)d_in[0];
    const float* W1     = (const float*)d_in[1];
    const float* b1     = (const float*)d_in[2];
    const float* W2     = (const float*)d_in[3];
    const float* b2     = (const float*)d_in[4];
    const float* proto  = (const float*)d_in[5];
    const float* last_w = (const float*)d_in[6];

    float* out = (float*)d_out;   // [32*200] logits, then [32*2000] min_dist

    // ws layout (~4.6MB): fT 2MB | x2buf 64KB | acts 256KB | ph 256KB | p2 8KB | md_part 2MB
    unsigned short* fT = (unsigned short*)d_ws;
    float* x2buf = (float*)(fT + (size_t)N_*L_*CP);
    float* acts  = x2buf + (size_t)N_*L_;
    unsigned short* ph = (unsigned short*)(acts + (size_t)N_*P_);
    float* p2      = (float*)(ph + (size_t)P_*CP);
    float* md_part = p2 + P_;

    k0_proto  <<<500,           256, 0, stream>>>(proto, ph, p2);
    k1_conv   <<<dim3(16, 32),  256, 0, stream>>>(x, W1, b1, W2, b2, fT, x2buf);
    k2_dist   <<<dim3(32, 32),  256, 0, stream>>>(fT, ph, x2buf, md_part);
    k2b_reduce<<<dim3(8, 32),   256, 0, stream>>>(md_part, p2, out + N_*NCLS, acts);
    k3_logits <<<1600,          256, 0, stream>>>(acts, last_w, out);
}